// Round 19
// baseline (266.121 us; speedup 1.0000x reference)
//
#include <hip/hip_runtime.h>
#include <math.h>

// ---------------------------------------------------------------------------
// LightAttention, bf16-MFMA pipeline v17.  B=8,C=16,S=512,N=512,V=128.
// v17 = v16 (230.7-230.9us plateau) + launch-graph compaction: k_qat and k_v
// are independent (both only need k_wx/k_kr outputs) -> merged into one
// 1024-block kernel k_qv (blockIdx.x<4: qat path, else: v path). One launch
// saved; tails overlap. Both paths byte-identical to v16. absmax 0.03125.
// ---------------------------------------------------------------------------

typedef short  bf16x8 __attribute__((ext_vector_type(8)));
typedef short  short8 __attribute__((ext_vector_type(8)));
typedef float  f32x4  __attribute__((ext_vector_type(4)));

__device__ __forceinline__ unsigned short f2bf(float f) {
    union { float f; unsigned u; } v; v.f = f;
    return (unsigned short)((v.u + 0x7FFF + ((v.u >> 16) & 1)) >> 16);
}
__device__ __forceinline__ float bf2f(unsigned short u) {
    union { unsigned u; float f; } v; v.u = (unsigned)u << 16; return v.f;
}

__device__ __forceinline__ void gload16(const void* g, void* l)
{
    __builtin_amdgcn_global_load_lds(
        (const __attribute__((address_space(1))) void*)g,
        (__attribute__((address_space(3))) void*)l, 16, 0, 0);
}

// ---- workspace layout (bytes) ---------------------------------------------
constexpr size_t OB_XB   = 0;                          // yb
constexpr size_t OB_XT   = OB_XB  + 67108864;          // (unused)
constexpr size_t OB_KLB  = OB_XT  + 67108864;
constexpr size_t OB_V1LB = OB_KLB + 2097152;
constexpr size_t OB_V2WB = OB_V1LB+ 2097152;
constexpr size_t OB_WQT  = OB_V2WB+ 2097152;
constexpr size_t OB_KRT  = OB_WQT + 2097152;
constexpr size_t OB_V1RT = OB_KRT + 2097152;
constexpr size_t OB_BUF  = OB_V1RT+ 2097152;           // kx,v1x  32 MiB
constexpr size_t OB_V2T  = OB_BUF + 33554432;          // 16 MiB
constexpr size_t OB_KM   = OB_V2T + 16777216;          // 4 MiB
constexpr size_t OB_V1M  = OB_KM  + 4194304;           // 4 MiB
constexpr size_t OB_ATT  = OB_V1M + 4194304;           // 16 MiB
constexpr size_t OB_VT   = OB_ATT + 16777216;          // 16 MiB
constexpr size_t OB_ST   = OB_VT  + 16777216;          // stats

// ---------------------------------------------------------------------------
// MFMA tile core (global_load_lds, BK=64, XOR swizzle via global src addr).
// ---------------------------------------------------------------------------
template<int NSTEPS, int MF, int NF>
__device__ __forceinline__ void mmcore(const char* __restrict__ Ab, int ldaB,
                                       const char* __restrict__ Bb, int ldbB,
                                       f32x4 (&acc)[MF][NF],
                                       char* __restrict__ smA, char* __restrict__ smB,
                                       int wm, int wn)
{
    const int tid = threadIdx.x;
    const int w = tid >> 6, l = tid & 63, g = l >> 4, lr = l & 15;
    const int rl = l >> 3, ch = l & 7;

#pragma unroll 1
    for (int t = 0; t < NSTEPS; ++t) {
#pragma unroll
        for (int j = 0; j < 4; ++j) {
            const int row = w * 32 + j * 8 + rl;
            gload16(Ab + (size_t)row * ldaB + t * 128 + ((ch ^ (row & 7)) * 16),
                    smA + (w * 32 + j * 8) * 128);
        }
#pragma unroll
        for (int j = 0; j < 4; ++j) {
            const int row = w * 32 + j * 8 + rl;
            gload16(Bb + (size_t)row * ldbB + t * 128 + ((ch ^ (row & 7)) * 16),
                    smB + (w * 32 + j * 8) * 128);
        }
        __syncthreads();
#pragma unroll
        for (int ks = 0; ks < 2; ++ks) {
            bf16x8 av[MF], bv[NF];
            const int cc = ks * 4 + g;
#pragma unroll
            for (int i = 0; i < MF; ++i) { int rw = wm + i * 16 + lr;
                av[i] = *(const bf16x8*)(smA + rw * 128 + ((cc ^ (rw & 7)) * 16)); }
#pragma unroll
            for (int j = 0; j < NF; ++j) { int rw = wn + j * 16 + lr;
                bv[j] = *(const bf16x8*)(smB + rw * 128 + ((cc ^ (rw & 7)) * 16)); }
#pragma unroll
            for (int i = 0; i < MF; ++i)
#pragma unroll
                for (int j = 0; j < NF; ++j)
                    acc[i][j] = __builtin_amdgcn_mfma_f32_16x16x32_bf16(av[i], bv[j], acc[i][j], 0, 0, 0);
        }
        __syncthreads();
    }
}

// ---- LDS-staged epilogue (128x128 bf16 tile, 272B padded rows) ------------
__device__ __forceinline__ void epi_write_rm(const f32x4 (&acc)[4][4], char* sm)
{
    const int tid = threadIdx.x, w = tid >> 6, l = tid & 63, g = l >> 4, lr = l & 15;
    const int wm = (w >> 1) * 64, wn = (w & 1) * 64;
#pragma unroll
    for (int i = 0; i < 4; ++i)
#pragma unroll
        for (int j = 0; j < 4; ++j) {
            const int row = wm + i * 16 + g * 4, col = wn + j * 16 + lr;
#pragma unroll
            for (int r = 0; r < 4; ++r)
                *(unsigned short*)(sm + (row + r) * 272 + col * 2) = f2bf(acc[i][j][r]);
        }
}

__device__ __forceinline__ void epi_write_tr(const f32x4 (&acc)[4][4], char* sm)
{
    const int tid = threadIdx.x, w = tid >> 6, l = tid & 63, g = l >> 4, lr = l & 15;
    const int wm = (w >> 1) * 64, wn = (w & 1) * 64;
#pragma unroll
    for (int i = 0; i < 4; ++i)
#pragma unroll
        for (int j = 0; j < 4; ++j) {
            const int rv = wm + i * 16 + g * 4, cn = wn + j * 16 + lr;
            ushort4 pk = make_ushort4(f2bf(acc[i][j][0]), f2bf(acc[i][j][1]),
                                      f2bf(acc[i][j][2]), f2bf(acc[i][j][3]));
            *(ushort4*)(sm + cn * 272 + rv * 2) = pk;
        }
}

__device__ __forceinline__ void epi_flush(const char* sm, unsigned short* gout, int ldg)
{
    const int tid = threadIdx.x;
    const int r0 = tid >> 4, q = tid & 15;
#pragma unroll
    for (int rep = 0; rep < 8; ++rep) {
        const int row = rep * 16 + r0;
        *(short8*)((short*)gout + (size_t)row * ldg + q * 8) =
            *(const short8*)(sm + row * 272 + q * 16);
    }
    __syncthreads();
}

// ---- k_prep: stats zero + weight bf16 casts + weight transposes -----------
__global__ __launch_bounds__(256) void k_prep(const float* __restrict__ kl,
                                              const float* __restrict__ v1l,
                                              const float* __restrict__ v2w,
                                              const float* __restrict__ wq,
                                              const float* __restrict__ kr,
                                              const float* __restrict__ v1r,
                                              unsigned short* __restrict__ klb,
                                              unsigned short* __restrict__ v1lb,
                                              unsigned short* __restrict__ v2wb,
                                              unsigned short* __restrict__ wqt,
                                              unsigned short* __restrict__ krt,
                                              unsigned short* __restrict__ v1rt,
                                              float* __restrict__ stats)
{
    __shared__ float tl[64][65];
    const int id = blockIdx.x, tid = threadIdx.x;
    if (id == 0 && tid < 64) stats[tid] = 0.f;
    if (id < 192) {
        const int sel = id >> 6, blk = id & 63;
        const float* src = sel == 0 ? kl : sel == 1 ? v1l : v2w;
        unsigned short* dst = sel == 0 ? klb : sel == 1 ? v1lb : v2wb;
#pragma unroll
        for (int r = 0; r < 4; ++r) {
            const int i = blk * 1024 + r * 256 + tid;
            float4 v = ((const float4*)src)[i];
            ((ushort4*)dst)[i] = make_ushort4(f2bf(v.x), f2bf(v.y), f2bf(v.z), f2bf(v.w));
        }
        return;
    }
    const int id2 = id - 192;
    const int p = id2 >> 4, rem = id2 & 15, by = rem >> 1, bx = rem & 1;
    const int widx = p >> 4, c = p & 15;
    const float* s = (widx == 0 ? wq : widx == 1 ? kr : v1r) + (size_t)c * 65536;
    unsigned short* d = (widx == 0 ? wqt : widx == 1 ? krt : v1rt) + (size_t)c * 65536;
    const int r0 = by * 64, c0 = bx * 64;
    const int rr = tid >> 4, cc = (tid & 15) * 4;
#pragma unroll
    for (int rep = 0; rep < 4; ++rep) {
        int row = rep * 16 + rr;
        float4 v = *(const float4*)(s + (size_t)(r0 + row) * 128 + c0 + cc);
        tl[cc + 0][row] = v.x; tl[cc + 1][row] = v.y; tl[cc + 2][row] = v.z; tl[cc + 3][row] = v.w;
    }
    __syncthreads();
#pragma unroll
    for (int rep = 0; rep < 4; ++rep) {
        int crow = rep * 16 + rr;
        *(ushort4*)(d + (size_t)(c0 + crow) * 512 + r0 + cc) =
            make_ushort4(f2bf(tl[crow][cc]), f2bf(tl[crow][cc + 1]),
                         f2bf(tl[crow][cc + 2]), f2bf(tl[crow][cc + 3]));
    }
}

// ---- k_wx: two-sweep fused left GEMMs with in-kernel x transpose ----------
__global__ __launch_bounds__(256, 2) void k_wx(const unsigned short* __restrict__ klb,
                                               const unsigned short* __restrict__ v1lb,
                                               const unsigned short* __restrict__ v2wb,
                                               const float* __restrict__ x,
                                               unsigned short* __restrict__ bufb,
                                               unsigned short* __restrict__ v2t)
{
    __shared__ char smem[50176];         // 16K (W0) + 16K (W1) + 17408 (x^T)
    char* smA0 = smem;
    char* smA1 = smem + 16384;
    char* smX  = smem + 32768;
    const int n0 = blockIdx.x, bc = blockIdx.y, c = bc & 15;
    const char* Wb0 = (const char*)(klb  + (size_t)c * 65536);
    const char* Wb1 = (const char*)(v1lb + (size_t)c * 65536);
    const char* Wb2 = (const char*)(v2wb + (size_t)c * 65536);
    const float* xs = x + (size_t)bc * 262144 + n0 * 128;
    const int tid = threadIdx.x, w = tid >> 6, l = tid & 63, g = l >> 4, lr = l & 15;
    const int rl = l >> 3, ch = l & 7;
    const int wm = (w >> 1) * 64, wn = (w & 1) * 64;
    const int nq = (tid & 31) * 4, sp2 = (tid >> 5) * 2;

    float4 fr[8];
#pragma unroll
    for (int k = 0; k < 4; ++k) {
        const int sl = k * 16 + sp2;
        fr[k * 2 + 0] = *(const float4*)(xs + (size_t)(sl) * 512 + nq);
        fr[k * 2 + 1] = *(const float4*)(xs + (size_t)(sl + 1) * 512 + nq);
    }

    // ---- sweep A: kl (acc0) & v1l (acc1) share one x staging --------------
    f32x4 acc0[4][4] = {}, acc1[4][4] = {};
#pragma unroll 1
    for (int t = 0; t < 8; ++t) {
#pragma unroll
        for (int j = 0; j < 4; ++j) {
            const int row = w * 32 + j * 8 + rl;
            gload16(Wb0 + (size_t)row * 1024 + t * 128 + ((ch ^ (row & 7)) * 16),
                    smA0 + (w * 32 + j * 8) * 128);
        }
#pragma unroll
        for (int j = 0; j < 4; ++j) {
            const int row = w * 32 + j * 8 + rl;
            gload16(Wb1 + (size_t)row * 1024 + t * 128 + ((ch ^ (row & 7)) * 16),
                    smA1 + (w * 32 + j * 8) * 128);
        }
#pragma unroll
        for (int k = 0; k < 4; ++k) {
            const int sl = k * 16 + sp2;
            const float4 f0 = fr[k * 2 + 0];
            const float4 f1 = fr[k * 2 + 1];
            const unsigned p0 = f2bf(f0.x) | ((unsigned)f2bf(f1.x) << 16);
            const unsigned p1 = f2bf(f0.y) | ((unsigned)f2bf(f1.y) << 16);
            const unsigned p2 = f2bf(f0.z) | ((unsigned)f2bf(f1.z) << 16);
            const unsigned p3 = f2bf(f0.w) | ((unsigned)f2bf(f1.w) << 16);
            const int cl = sl >> 3, bic = (sl * 2) & 15;
#pragma unroll
            for (int i = 0; i < 4; ++i) {
                const int n = nq + i;
                const unsigned v = (i == 0) ? p0 : (i == 1) ? p1 : (i == 2) ? p2 : p3;
                *(unsigned*)(smX + n * 136 + ((cl ^ (n & 7)) << 4) + bic) = v;
            }
        }
        __syncthreads();
        if (t < 7) {
#pragma unroll
            for (int k = 0; k < 4; ++k) {
                const int sl = k * 16 + sp2;
                fr[k * 2 + 0] = *(const float4*)(xs + (size_t)((t + 1) * 64 + sl) * 512 + nq);
                fr[k * 2 + 1] = *(const float4*)(xs + (size_t)((t + 1) * 64 + sl + 1) * 512 + nq);
            }
        }
#pragma unroll
        for (int ks = 0; ks < 2; ++ks) {
            const int cc = ks * 4 + g;
            bf16x8 av[4], bv[4];
#pragma unroll
            for (int j = 0; j < 4; ++j) {
                const int n = wn + j * 16 + lr;
                const char* p = smX + n * 136 + ((cc ^ (n & 7)) << 4);
                union { unsigned long long u[2]; bf16x8 v; } tmp;
                tmp.u[0] = *(const unsigned long long*)(p);
                tmp.u[1] = *(const unsigned long long*)(p + 8);
                bv[j] = tmp.v;
            }
#pragma unroll
            for (int i = 0; i < 4; ++i) { const int rw = wm + i * 16 + lr;
                av[i] = *(const bf16x8*)(smA0 + rw * 128 + ((cc ^ (rw & 7)) * 16)); }
#pragma unroll
            for (int i = 0; i < 4; ++i)
#pragma unroll
                for (int j = 0; j < 4; ++j)
                    acc0[i][j] = __builtin_amdgcn_mfma_f32_16x16x32_bf16(av[i], bv[j], acc0[i][j], 0, 0, 0);
#pragma unroll
            for (int i = 0; i < 4; ++i) { const int rw = wm + i * 16 + lr;
                av[i] = *(const bf16x8*)(smA1 + rw * 128 + ((cc ^ (rw & 7)) * 16)); }
#pragma unroll
            for (int i = 0; i < 4; ++i)
#pragma unroll
                for (int j = 0; j < 4; ++j)
                    acc1[i][j] = __builtin_amdgcn_mfma_f32_16x16x32_bf16(av[i], bv[j], acc1[i][j], 0, 0, 0);
        }
        __syncthreads();
    }
    // sweep-B x preload issued BEFORE the epilogues (latency hidden under them)
#pragma unroll
    for (int k = 0; k < 4; ++k) {
        const int sl = k * 16 + sp2;
        fr[k * 2 + 0] = *(const float4*)(xs + (size_t)(sl) * 512 + nq);
        fr[k * 2 + 1] = *(const float4*)(xs + (size_t)(sl + 1) * 512 + nq);
    }
    epi_write_rm(acc0, smem);
    __syncthreads();
    epi_flush(smem, bufb + (size_t)bc * 131072 + n0 * 128, 512);
    epi_write_rm(acc1, smem);
    __syncthreads();
    epi_flush(smem, bufb + (size_t)bc * 131072 + 65536 + n0 * 128, 512);

    // ---- sweep B: v2w (x re-staged, L3-hot) --------------------------------
    f32x4 acc2[4][4] = {};
#pragma unroll 1
    for (int t = 0; t < 8; ++t) {
#pragma unroll
        for (int j = 0; j < 4; ++j) {
            const int row = w * 32 + j * 8 + rl;
            gload16(Wb2 + (size_t)row * 1024 + t * 128 + ((ch ^ (row & 7)) * 16),
                    smA0 + (w * 32 + j * 8) * 128);
        }
#pragma unroll
        for (int k = 0; k < 4; ++k) {
            const int sl = k * 16 + sp2;
            const float4 f0 = fr[k * 2 + 0];
            const float4 f1 = fr[k * 2 + 1];
            const unsigned p0 = f2bf(f0.x) | ((unsigned)f2bf(f1.x) << 16);
            const unsigned p1 = f2bf(f0.y) | ((unsigned)f2bf(f1.y) << 16);
            const unsigned p2 = f2bf(f0.z) | ((unsigned)f2bf(f1.z) << 16);
            const unsigned p3 = f2bf(f0.w) | ((unsigned)f2bf(f1.w) << 16);
            const int cl = sl >> 3, bic = (sl * 2) & 15;
#pragma unroll
            for (int i = 0; i < 4; ++i) {
                const int n = nq + i;
                const unsigned v = (i == 0) ? p0 : (i == 1) ? p1 : (i == 2) ? p2 : p3;
                *(unsigned*)(smX + n * 136 + ((cl ^ (n & 7)) << 4) + bic) = v;
            }
        }
        __syncthreads();
        if (t < 7) {
#pragma unroll
            for (int k = 0; k < 4; ++k) {
                const int sl = k * 16 + sp2;
                fr[k * 2 + 0] = *(const float4*)(xs + (size_t)((t + 1) * 64 + sl) * 512 + nq);
                fr[k * 2 + 1] = *(const float4*)(xs + (size_t)((t + 1) * 64 + sl + 1) * 512 + nq);
            }
        }
#pragma unroll
        for (int ks = 0; ks < 2; ++ks) {
            const int cc = ks * 4 + g;
            bf16x8 av[4], bv[4];
#pragma unroll
            for (int i = 0; i < 4; ++i) { const int rw = wm + i * 16 + lr;
                av[i] = *(const bf16x8*)(smA0 + rw * 128 + ((cc ^ (rw & 7)) * 16)); }
#pragma unroll
            for (int j = 0; j < 4; ++j) {
                const int n = wn + j * 16 + lr;
                const char* p = smX + n * 136 + ((cc ^ (n & 7)) << 4);
                union { unsigned long long u[2]; bf16x8 v; } tmp;
                tmp.u[0] = *(const unsigned long long*)(p);
                tmp.u[1] = *(const unsigned long long*)(p + 8);
                bv[j] = tmp.v;
            }
#pragma unroll
            for (int i = 0; i < 4; ++i)
#pragma unroll
                for (int j = 0; j < 4; ++j)
                    acc2[i][j] = __builtin_amdgcn_mfma_f32_16x16x32_bf16(av[i], bv[j], acc2[i][j], 0, 0, 0);
        }
        __syncthreads();
    }
    epi_write_tr(acc2, smem);
    __syncthreads();
    epi_flush(smem, v2t + (size_t)bc * 65536 + (size_t)n0 * 16384, 128);
}

// ---- k_kr: kx@krt -> kmat ; v1x@v1rt -> v1m -------------------------------
__global__ __launch_bounds__(256, 2) void k_kr(const unsigned short* __restrict__ bufb,
                                               const unsigned short* __restrict__ krt,
                                               const unsigned short* __restrict__ v1rt,
                                               unsigned short* __restrict__ kmat,
                                               unsigned short* __restrict__ v1m)
{
    __shared__ char smem[34816];
    char* smA = smem; char* smB = smem + 16384;
    const int mt = blockIdx.x, bc = blockIdx.y, c = bc & 15;
    const int w = threadIdx.x >> 6;
    f32x4 acc[4][4] = {};
    mmcore<8, 4, 4>((const char*)(bufb + (size_t)bc * 131072 + (size_t)mt * 65536), 1024,
                    (const char*)((mt ? v1rt : krt) + (size_t)c * 65536), 1024, acc, smA, smB,
                    (w >> 1) * 64, (w & 1) * 64);
    epi_write_rm(acc, smem);
    __syncthreads();
    epi_flush(smem, (mt ? v1m : kmat) + (size_t)bc * 16384, 128);
}

// ---- k_qv: merged k_qat (blockIdx.x<4) and k_v (blockIdx.x>=4) ------------
__global__ __launch_bounds__(256, 2) void k_qv(const float* __restrict__ x,
                                               const unsigned short* __restrict__ wqt,
                                               const unsigned short* __restrict__ kmat,
                                               const unsigned short* __restrict__ v2t,
                                               const unsigned short* __restrict__ v1m,
                                               unsigned short* __restrict__ attn,
                                               unsigned short* __restrict__ vt)
{
    __shared__ char smem[49152];
    const int bx = blockIdx.x, bc = blockIdx.y, c = bc & 15;
    const int tid = threadIdx.x, w = tid >> 6, l = tid & 63, g = l >> 4, lr = l & 15;
    const int rl = l >> 3, ch = l & 7;
    const int wm = (w >> 1) * 64, wn = (w & 1) * 64;

    if (bx >= 4) {
        // ---------------- k_v path: vt = v2t @ v1m^T-form ------------------
        const int mt = bx - 4;
        char* smA = smem; char* smB = smem + 16384;
        f32x4 acc[4][4] = {};
        mmcore<2, 4, 4>((const char*)(v2t + (size_t)bc * 65536 + (size_t)mt * 16384), 256,
                        (const char*)(v1m + (size_t)bc * 16384), 256, acc, smA, smB, wm, wn);
        epi_write_rm(acc, smem);
        __syncthreads();
        epi_flush(smem, vt + (size_t)bc * 65536 + (size_t)mt * 16384, 128);
        return;
    }

    // ---------------- k_qat path ------------------------------------------
    const int mt = bx;
    char* smA  = smem;
    char* smB  = smem + 16384;
    char* qlds = smem;               // q tile over dead GEMM1 staging
    char* smB2 = smem + 32768;       // GEMM2 B staging

    f32x4 acc[4][4] = {};
    {
        const float* Ax = x + (size_t)bc * 262144 + (size_t)(mt * 128) * 512;
        const char* Bw = (const char*)(wqt + (size_t)c * 65536);
        const int ar = tid >> 4, fq = tid & 15;
#pragma unroll 1
        for (int t = 0; t < 8; ++t) {
#pragma unroll
            for (int j = 0; j < 4; ++j) {
                const int row = w * 32 + j * 8 + rl;
                gload16(Bw + (size_t)row * 1024 + t * 128 + ((ch ^ (row & 7)) * 16),
                        smB + (w * 32 + j * 8) * 128);
            }
            float4 frq[8];
#pragma unroll
            for (int it = 0; it < 8; ++it) {
                const int row = it * 16 + ar;
                frq[it] = *(const float4*)(Ax + (size_t)row * 512 + t * 64 + fq * 4);
            }
#pragma unroll
            for (int it = 0; it < 8; ++it) {
                const int row = it * 16 + ar;
                ushort4 o = make_ushort4(f2bf(frq[it].x), f2bf(frq[it].y),
                                         f2bf(frq[it].z), f2bf(frq[it].w));
                *(ushort4*)(smA + row * 128 + (((fq >> 1) ^ (row & 7)) * 16) + (fq & 1) * 8) = o;
            }
            __syncthreads();
#pragma unroll
            for (int ks = 0; ks < 2; ++ks) {
                const int cc2 = ks * 4 + g;
                bf16x8 av[4], bv[4];
#pragma unroll
                for (int i = 0; i < 4; ++i) { const int rw = wm + i * 16 + lr;
                    av[i] = *(const bf16x8*)(smA + rw * 128 + ((cc2 ^ (rw & 7)) * 16)); }
#pragma unroll
                for (int j = 0; j < 4; ++j) { const int rw = wn + j * 16 + lr;
                    bv[j] = *(const bf16x8*)(smB + rw * 128 + ((cc2 ^ (rw & 7)) * 16)); }
#pragma unroll
                for (int i = 0; i < 4; ++i)
#pragma unroll
                    for (int j = 0; j < 4; ++j)
                        acc[i][j] = __builtin_amdgcn_mfma_f32_16x16x32_bf16(av[i], bv[j], acc[i][j], 0, 0, 0);
            }
            __syncthreads();
        }
    }
    {
        const int t = wn >> 6;
#pragma unroll
        for (int i = 0; i < 4; ++i)
#pragma unroll
            for (int j = 0; j < 4; ++j) {
                const int k6 = j * 16 + lr;
                const int chunk = k6 >> 3, eb = (k6 & 7) << 1;
#pragma unroll
                for (int r = 0; r < 4; ++r) {
                    const int row = wm + i * 16 + g * 4 + r;
                    *(unsigned short*)(qlds + t * 16384 + row * 128 +
                                       ((chunk ^ (row & 7)) << 4) + eb) = f2bf(acc[i][j][r]);
                }
            }
    }
    __syncthreads();

    f32x4 acc2[2][8] = {};
    const char* Kb = (const char*)(kmat + (size_t)bc * 16384);
#pragma unroll
    for (int t = 0; t < 2; ++t) {
#pragma unroll
        for (int j = 0; j < 4; ++j) {
            const int row = w * 32 + j * 8 + rl;
            gload16(Kb + (size_t)row * 256 + t * 128 + ((ch ^ (row & 7)) * 16),
                    smB2 + (w * 32 + j * 8) * 128);
        }
        __syncthreads();
#pragma unroll
        for (int ks = 0; ks < 2; ++ks) {
            const int cc2 = ks * 4 + g;
            bf16x8 av[2], bv[8];
#pragma unroll
            for (int i = 0; i < 2; ++i) { const int rw = w * 32 + i * 16 + lr;
                av[i] = *(const bf16x8*)(qlds + t * 16384 + rw * 128 + ((cc2 ^ (rw & 7)) * 16)); }
#pragma unroll
            for (int j = 0; j < 8; ++j) { const int rw = j * 16 + lr;
                bv[j] = *(const bf16x8*)(smB2 + rw * 128 + ((cc2 ^ (rw & 7)) * 16)); }
#pragma unroll
            for (int i = 0; i < 2; ++i)
#pragma unroll
                for (int j = 0; j < 8; ++j)
                    acc2[i][j] = __builtin_amdgcn_mfma_f32_16x16x32_bf16(av[i], bv[j], acc2[i][j], 0, 0, 0);
        }
        __syncthreads();
    }

    char* wsl = smem + w * 8704;
    unsigned short* ob = attn + (size_t)bc * 65536 + (size_t)(mt * 128 + w * 32) * 128;
#pragma unroll
    for (int i = 0; i < 2; ++i)
#pragma unroll
        for (int r = 0; r < 4; ++r) {
            float mx = -3e38f;
#pragma unroll
            for (int fj = 0; fj < 8; ++fj) mx = fmaxf(mx, acc2[i][fj][r]);
#pragma unroll
            for (int d = 1; d < 16; d <<= 1) mx = fmaxf(mx, __shfl_xor(mx, d));
            float s = 0.f, e[8];
#pragma unroll
            for (int fj = 0; fj < 8; ++fj) { e[fj] = __expf(acc2[i][fj][r] - mx); s += e[fj]; }
#pragma unroll
            for (int d = 1; d < 16; d <<= 1) s += __shfl_xor(s, d);
            const float inv = 1.f / s;
            const int rowh = i * 16 + g * 4 + r;
#pragma unroll
            for (int fj = 0; fj < 8; ++fj)
                *(unsigned short*)(wsl + rowh * 272 + (fj * 16 + lr) * 2) = f2bf(e[fj] * inv);
        }
#pragma unroll
    for (int rep = 0; rep < 8; ++rep) {
        const int row = rep * 4 + (l >> 4);
        *(short8*)((short*)ob + (size_t)row * 128 + (l & 15) * 8) =
            *(const short8*)(wsl + row * 272 + (l & 15) * 16);
    }
}

// ---- k_y: y = x + attn@v (fp32), stats, store y as bf16 -------------------
__global__ __launch_bounds__(256, 2) void k_y(const unsigned short* __restrict__ attn,
                                              const unsigned short* __restrict__ vt,
                                              const float* __restrict__ x,
                                              unsigned short* __restrict__ yb,
                                              float* __restrict__ stats)
{
    __shared__ char smem[34816];
    __shared__ float r1[4], r2[4];
    char* smA = smem; char* smB = smem + 16384;
    const int nx = blockIdx.x, my = blockIdx.y, bc = blockIdx.z, c = bc & 15;
    const int tid = threadIdx.x, w = tid >> 6, l = tid & 63, g = l >> 4, lr = l & 15;
    f32x4 acc[4][4] = {};
    mmcore<2, 4, 4>((const char*)(attn + (size_t)bc * 65536 + (size_t)my * 16384), 256,
                    (const char*)(vt + (size_t)bc * 65536 + (size_t)nx * 16384), 256, acc, smA, smB,
                    (w >> 1) * 64, (w & 1) * 64);
    const float* xw = x + (size_t)bc * 262144 + (size_t)my * 128 * 512 + nx * 128;
    const int wm = (w >> 1) * 64, wn = (w & 1) * 64;
    float lsum = 0.f, lss = 0.f;
#pragma unroll
    for (int i = 0; i < 4; ++i)
#pragma unroll
        for (int j = 0; j < 4; ++j)
#pragma unroll
            for (int r = 0; r < 4; ++r) {
                const int row = wm + i * 16 + g * 4 + r, col = wn + j * 16 + lr;
                const float yv = acc[i][j][r] + xw[(size_t)row * 512 + col];
                lsum += yv; lss += yv * yv;
                *(unsigned short*)(smem + row * 272 + col * 2) = f2bf(yv);
            }
#pragma unroll
    for (int d = 32; d >= 1; d >>= 1) { lsum += __shfl_xor(lsum, d); lss += __shfl_xor(lss, d); }
    if (l == 0) { r1[w] = lsum; r2[w] = lss; }
    __syncthreads();
    epi_flush(smem, yb + (size_t)bc * 262144 + (size_t)my * 128 * 512 + nx * 128, 512);
    if (tid == 0) {
        atomicAdd(&stats[c * 2 + 0], r1[0] + r1[1] + r1[2] + r1[3]);
        atomicAdd(&stats[c * 2 + 1], r2[0] + r2[1] + r2[2] + r2[3]);
    }
}

// out(fp32) = yb(bf16)*scale[c] + shift[c], finalize inlined via LDS
__global__ __launch_bounds__(256) void k_norm(const unsigned short* __restrict__ yb,
                                              float* __restrict__ out,
                                              const float* __restrict__ stats,
                                              const float* __restrict__ gamma,
                                              const float* __restrict__ beta)
{
    __shared__ float ssc[16], ssh[16];
    if (threadIdx.x < 16) {
        const int c = threadIdx.x;
        const float cnt  = 2097152.f;
        const float mean = stats[c * 2 + 0] / cnt;
        const float var  = stats[c * 2 + 1] / cnt - mean * mean;
        const float sc   = rsqrtf(var + 1e-5f) * gamma[c];
        ssc[c] = sc;
        ssh[c] = beta[c] - mean * sc;
    }
    __syncthreads();
    const int tot = 4194304;
    for (int i = blockIdx.x * 256 + threadIdx.x; i < tot; i += gridDim.x * 256) {
        const long e = (long)i * 8;
        const int c = (int)(e >> 18) & 15;
        const float sc = ssc[c];
        const float sh = ssh[c];
        short8 v = ((const short8*)yb)[i];
        float4 o0, o1;
        o0.x = bf2f((unsigned short)v[0]) * sc + sh;
        o0.y = bf2f((unsigned short)v[1]) * sc + sh;
        o0.z = bf2f((unsigned short)v[2]) * sc + sh;
        o0.w = bf2f((unsigned short)v[3]) * sc + sh;
        o1.x = bf2f((unsigned short)v[4]) * sc + sh;
        o1.y = bf2f((unsigned short)v[5]) * sc + sh;
        o1.z = bf2f((unsigned short)v[6]) * sc + sh;
        o1.w = bf2f((unsigned short)v[7]) * sc + sh;
        ((float4*)out)[(size_t)i * 2 + 0] = o0;
        ((float4*)out)[(size_t)i * 2 + 1] = o1;
    }
}

extern "C" void kernel_launch(void* const* d_in, const int* in_sizes, int n_in,
                              void* d_out, int out_size, void* d_ws, size_t ws_size,
                              hipStream_t stream)
{
    (void)in_sizes; (void)n_in; (void)out_size; (void)ws_size;
    const float* x     = (const float*)d_in[0];
    const float* wq    = (const float*)d_in[1];
    const float* kl    = (const float*)d_in[2];
    const float* kr    = (const float*)d_in[3];
    const float* v1l   = (const float*)d_in[4];
    const float* v1r   = (const float*)d_in[5];
    const float* v2w   = (const float*)d_in[6];
    const float* gamma = (const float*)d_in[7];
    const float* beta  = (const float*)d_in[8];
    float* out = (float*)d_out;
    char*  ws  = (char*)d_ws;

    unsigned short* yb   = (unsigned short*)(ws + OB_XB);
    unsigned short* klb  = (unsigned short*)(ws + OB_KLB);
    unsigned short* v1lb = (unsigned short*)(ws + OB_V1LB);
    unsigned short* v2wb = (unsigned short*)(ws + OB_V2WB);
    unsigned short* wqt  = (unsigned short*)(ws + OB_WQT);
    unsigned short* krt  = (unsigned short*)(ws + OB_KRT);
    unsigned short* v1rt = (unsigned short*)(ws + OB_V1RT);
    unsigned short* bufb = (unsigned short*)(ws + OB_BUF);
    unsigned short* v2t  = (unsigned short*)(ws + OB_V2T);
    unsigned short* kmat = (unsigned short*)(ws + OB_KM);
    unsigned short* v1m  = (unsigned short*)(ws + OB_V1M);
    unsigned short* attn = (unsigned short*)(ws + OB_ATT);
    unsigned short* vt   = (unsigned short*)(ws + OB_VT);
    float*          st   = (float*)(ws + OB_ST);

    hipLaunchKernelGGL(k_prep,  dim3(960),       dim3(256), 0, stream,
                       kl, v1l, v2w, wq, kr, v1r, klb, v1lb, v2wb, wqt, krt, v1rt, st);
    hipLaunchKernelGGL(k_wx,    dim3(4, 128),    dim3(256), 0, stream, klb, v1lb, v2wb, x, bufb, v2t);
    hipLaunchKernelGGL(k_kr,    dim3(2, 128),    dim3(256), 0, stream, bufb, krt, v1rt, kmat, v1m);
    hipLaunchKernelGGL(k_qv,    dim3(8, 128),    dim3(256), 0, stream, x, wqt, kmat, v2t, v1m, attn, vt);
    hipLaunchKernelGGL(k_y,     dim3(4, 4, 128), dim3(256), 0, stream, attn, vt, x, yb, st);
    hipLaunchKernelGGL(k_norm,  dim3(2048),      dim3(256), 0, stream, yb, out, st, gamma, beta);
}

// Round 20
// 230.696 us; speedup vs baseline: 1.1536x; 1.1536x over previous
//
#include <hip/hip_runtime.h>
#include <math.h>

// ---------------------------------------------------------------------------
// LightAttention, bf16-MFMA pipeline v18 = v16 restored (best: 230.7-230.9us).
// v17's qat+v merge regressed (heterogeneous block paths wreck CU packing).
// Final structure: 6 launches + k_norm; two-sweep k_wx; fused k_qat;
// fp32 residual/softmax/stats; absmax 0.03125.
// ---------------------------------------------------------------------------

typedef short  bf16x8 __attribute__((ext_vector_type(8)));
typedef short  short8 __attribute__((ext_vector_type(8)));
typedef float  f32x4  __attribute__((ext_vector_type(4)));

__device__ __forceinline__ unsigned short f2bf(float f) {
    union { float f; unsigned u; } v; v.f = f;
    return (unsigned short)((v.u + 0x7FFF + ((v.u >> 16) & 1)) >> 16);
}
__device__ __forceinline__ float bf2f(unsigned short u) {
    union { unsigned u; float f; } v; v.u = (unsigned)u << 16; return v.f;
}

__device__ __forceinline__ void gload16(const void* g, void* l)
{
    __builtin_amdgcn_global_load_lds(
        (const __attribute__((address_space(1))) void*)g,
        (__attribute__((address_space(3))) void*)l, 16, 0, 0);
}

// ---- workspace layout (bytes) ---------------------------------------------
constexpr size_t OB_XB   = 0;                          // yb
constexpr size_t OB_XT   = OB_XB  + 67108864;          // (unused)
constexpr size_t OB_KLB  = OB_XT  + 67108864;
constexpr size_t OB_V1LB = OB_KLB + 2097152;
constexpr size_t OB_V2WB = OB_V1LB+ 2097152;
constexpr size_t OB_WQT  = OB_V2WB+ 2097152;
constexpr size_t OB_KRT  = OB_WQT + 2097152;
constexpr size_t OB_V1RT = OB_KRT + 2097152;
constexpr size_t OB_BUF  = OB_V1RT+ 2097152;           // kx,v1x  32 MiB
constexpr size_t OB_V2T  = OB_BUF + 33554432;          // 16 MiB
constexpr size_t OB_KM   = OB_V2T + 16777216;          // 4 MiB
constexpr size_t OB_V1M  = OB_KM  + 4194304;           // 4 MiB
constexpr size_t OB_ATT  = OB_V1M + 4194304;           // 16 MiB
constexpr size_t OB_VT   = OB_ATT + 16777216;          // 16 MiB
constexpr size_t OB_ST   = OB_VT  + 16777216;          // stats

// ---------------------------------------------------------------------------
// MFMA tile core (global_load_lds, BK=64, XOR swizzle via global src addr).
// ---------------------------------------------------------------------------
template<int NSTEPS, int MF, int NF>
__device__ __forceinline__ void mmcore(const char* __restrict__ Ab, int ldaB,
                                       const char* __restrict__ Bb, int ldbB,
                                       f32x4 (&acc)[MF][NF],
                                       char* __restrict__ smA, char* __restrict__ smB,
                                       int wm, int wn)
{
    const int tid = threadIdx.x;
    const int w = tid >> 6, l = tid & 63, g = l >> 4, lr = l & 15;
    const int rl = l >> 3, ch = l & 7;

#pragma unroll 1
    for (int t = 0; t < NSTEPS; ++t) {
#pragma unroll
        for (int j = 0; j < 4; ++j) {
            const int row = w * 32 + j * 8 + rl;
            gload16(Ab + (size_t)row * ldaB + t * 128 + ((ch ^ (row & 7)) * 16),
                    smA + (w * 32 + j * 8) * 128);
        }
#pragma unroll
        for (int j = 0; j < 4; ++j) {
            const int row = w * 32 + j * 8 + rl;
            gload16(Bb + (size_t)row * ldbB + t * 128 + ((ch ^ (row & 7)) * 16),
                    smB + (w * 32 + j * 8) * 128);
        }
        __syncthreads();
#pragma unroll
        for (int ks = 0; ks < 2; ++ks) {
            bf16x8 av[MF], bv[NF];
            const int cc = ks * 4 + g;
#pragma unroll
            for (int i = 0; i < MF; ++i) { int rw = wm + i * 16 + lr;
                av[i] = *(const bf16x8*)(smA + rw * 128 + ((cc ^ (rw & 7)) * 16)); }
#pragma unroll
            for (int j = 0; j < NF; ++j) { int rw = wn + j * 16 + lr;
                bv[j] = *(const bf16x8*)(smB + rw * 128 + ((cc ^ (rw & 7)) * 16)); }
#pragma unroll
            for (int i = 0; i < MF; ++i)
#pragma unroll
                for (int j = 0; j < NF; ++j)
                    acc[i][j] = __builtin_amdgcn_mfma_f32_16x16x32_bf16(av[i], bv[j], acc[i][j], 0, 0, 0);
        }
        __syncthreads();
    }
}

// ---- LDS-staged epilogue (128x128 bf16 tile, 272B padded rows) ------------
__device__ __forceinline__ void epi_write_rm(const f32x4 (&acc)[4][4], char* sm)
{
    const int tid = threadIdx.x, w = tid >> 6, l = tid & 63, g = l >> 4, lr = l & 15;
    const int wm = (w >> 1) * 64, wn = (w & 1) * 64;
#pragma unroll
    for (int i = 0; i < 4; ++i)
#pragma unroll
        for (int j = 0; j < 4; ++j) {
            const int row = wm + i * 16 + g * 4, col = wn + j * 16 + lr;
#pragma unroll
            for (int r = 0; r < 4; ++r)
                *(unsigned short*)(sm + (row + r) * 272 + col * 2) = f2bf(acc[i][j][r]);
        }
}

__device__ __forceinline__ void epi_write_tr(const f32x4 (&acc)[4][4], char* sm)
{
    const int tid = threadIdx.x, w = tid >> 6, l = tid & 63, g = l >> 4, lr = l & 15;
    const int wm = (w >> 1) * 64, wn = (w & 1) * 64;
#pragma unroll
    for (int i = 0; i < 4; ++i)
#pragma unroll
        for (int j = 0; j < 4; ++j) {
            const int rv = wm + i * 16 + g * 4, cn = wn + j * 16 + lr;
            ushort4 pk = make_ushort4(f2bf(acc[i][j][0]), f2bf(acc[i][j][1]),
                                      f2bf(acc[i][j][2]), f2bf(acc[i][j][3]));
            *(ushort4*)(sm + cn * 272 + rv * 2) = pk;
        }
}

__device__ __forceinline__ void epi_flush(const char* sm, unsigned short* gout, int ldg)
{
    const int tid = threadIdx.x;
    const int r0 = tid >> 4, q = tid & 15;
#pragma unroll
    for (int rep = 0; rep < 8; ++rep) {
        const int row = rep * 16 + r0;
        *(short8*)((short*)gout + (size_t)row * ldg + q * 8) =
            *(const short8*)(sm + row * 272 + q * 16);
    }
    __syncthreads();
}

// ---- k_prep: stats zero + weight bf16 casts + weight transposes -----------
__global__ __launch_bounds__(256) void k_prep(const float* __restrict__ kl,
                                              const float* __restrict__ v1l,
                                              const float* __restrict__ v2w,
                                              const float* __restrict__ wq,
                                              const float* __restrict__ kr,
                                              const float* __restrict__ v1r,
                                              unsigned short* __restrict__ klb,
                                              unsigned short* __restrict__ v1lb,
                                              unsigned short* __restrict__ v2wb,
                                              unsigned short* __restrict__ wqt,
                                              unsigned short* __restrict__ krt,
                                              unsigned short* __restrict__ v1rt,
                                              float* __restrict__ stats)
{
    __shared__ float tl[64][65];
    const int id = blockIdx.x, tid = threadIdx.x;
    if (id == 0 && tid < 64) stats[tid] = 0.f;
    if (id < 192) {
        const int sel = id >> 6, blk = id & 63;
        const float* src = sel == 0 ? kl : sel == 1 ? v1l : v2w;
        unsigned short* dst = sel == 0 ? klb : sel == 1 ? v1lb : v2wb;
#pragma unroll
        for (int r = 0; r < 4; ++r) {
            const int i = blk * 1024 + r * 256 + tid;
            float4 v = ((const float4*)src)[i];
            ((ushort4*)dst)[i] = make_ushort4(f2bf(v.x), f2bf(v.y), f2bf(v.z), f2bf(v.w));
        }
        return;
    }
    const int id2 = id - 192;
    const int p = id2 >> 4, rem = id2 & 15, by = rem >> 1, bx = rem & 1;
    const int widx = p >> 4, c = p & 15;
    const float* s = (widx == 0 ? wq : widx == 1 ? kr : v1r) + (size_t)c * 65536;
    unsigned short* d = (widx == 0 ? wqt : widx == 1 ? krt : v1rt) + (size_t)c * 65536;
    const int r0 = by * 64, c0 = bx * 64;
    const int rr = tid >> 4, cc = (tid & 15) * 4;
#pragma unroll
    for (int rep = 0; rep < 4; ++rep) {
        int row = rep * 16 + rr;
        float4 v = *(const float4*)(s + (size_t)(r0 + row) * 128 + c0 + cc);
        tl[cc + 0][row] = v.x; tl[cc + 1][row] = v.y; tl[cc + 2][row] = v.z; tl[cc + 3][row] = v.w;
    }
    __syncthreads();
#pragma unroll
    for (int rep = 0; rep < 4; ++rep) {
        int crow = rep * 16 + rr;
        *(ushort4*)(d + (size_t)(c0 + crow) * 512 + r0 + cc) =
            make_ushort4(f2bf(tl[crow][cc]), f2bf(tl[crow][cc + 1]),
                         f2bf(tl[crow][cc + 2]), f2bf(tl[crow][cc + 3]));
    }
}

// ---- k_wx: two-sweep fused left GEMMs with in-kernel x transpose ----------
__global__ __launch_bounds__(256, 2) void k_wx(const unsigned short* __restrict__ klb,
                                               const unsigned short* __restrict__ v1lb,
                                               const unsigned short* __restrict__ v2wb,
                                               const float* __restrict__ x,
                                               unsigned short* __restrict__ bufb,
                                               unsigned short* __restrict__ v2t)
{
    __shared__ char smem[50176];         // 16K (W0) + 16K (W1) + 17408 (x^T)
    char* smA0 = smem;
    char* smA1 = smem + 16384;
    char* smX  = smem + 32768;
    const int n0 = blockIdx.x, bc = blockIdx.y, c = bc & 15;
    const char* Wb0 = (const char*)(klb  + (size_t)c * 65536);
    const char* Wb1 = (const char*)(v1lb + (size_t)c * 65536);
    const char* Wb2 = (const char*)(v2wb + (size_t)c * 65536);
    const float* xs = x + (size_t)bc * 262144 + n0 * 128;
    const int tid = threadIdx.x, w = tid >> 6, l = tid & 63, g = l >> 4, lr = l & 15;
    const int rl = l >> 3, ch = l & 7;
    const int wm = (w >> 1) * 64, wn = (w & 1) * 64;
    const int nq = (tid & 31) * 4, sp2 = (tid >> 5) * 2;

    float4 fr[8];
#pragma unroll
    for (int k = 0; k < 4; ++k) {
        const int sl = k * 16 + sp2;
        fr[k * 2 + 0] = *(const float4*)(xs + (size_t)(sl) * 512 + nq);
        fr[k * 2 + 1] = *(const float4*)(xs + (size_t)(sl + 1) * 512 + nq);
    }

    // ---- sweep A: kl (acc0) & v1l (acc1) share one x staging --------------
    f32x4 acc0[4][4] = {}, acc1[4][4] = {};
#pragma unroll 1
    for (int t = 0; t < 8; ++t) {
#pragma unroll
        for (int j = 0; j < 4; ++j) {
            const int row = w * 32 + j * 8 + rl;
            gload16(Wb0 + (size_t)row * 1024 + t * 128 + ((ch ^ (row & 7)) * 16),
                    smA0 + (w * 32 + j * 8) * 128);
        }
#pragma unroll
        for (int j = 0; j < 4; ++j) {
            const int row = w * 32 + j * 8 + rl;
            gload16(Wb1 + (size_t)row * 1024 + t * 128 + ((ch ^ (row & 7)) * 16),
                    smA1 + (w * 32 + j * 8) * 128);
        }
#pragma unroll
        for (int k = 0; k < 4; ++k) {
            const int sl = k * 16 + sp2;
            const float4 f0 = fr[k * 2 + 0];
            const float4 f1 = fr[k * 2 + 1];
            const unsigned p0 = f2bf(f0.x) | ((unsigned)f2bf(f1.x) << 16);
            const unsigned p1 = f2bf(f0.y) | ((unsigned)f2bf(f1.y) << 16);
            const unsigned p2 = f2bf(f0.z) | ((unsigned)f2bf(f1.z) << 16);
            const unsigned p3 = f2bf(f0.w) | ((unsigned)f2bf(f1.w) << 16);
            const int cl = sl >> 3, bic = (sl * 2) & 15;
#pragma unroll
            for (int i = 0; i < 4; ++i) {
                const int n = nq + i;
                const unsigned v = (i == 0) ? p0 : (i == 1) ? p1 : (i == 2) ? p2 : p3;
                *(unsigned*)(smX + n * 136 + ((cl ^ (n & 7)) << 4) + bic) = v;
            }
        }
        __syncthreads();
        if (t < 7) {
#pragma unroll
            for (int k = 0; k < 4; ++k) {
                const int sl = k * 16 + sp2;
                fr[k * 2 + 0] = *(const float4*)(xs + (size_t)((t + 1) * 64 + sl) * 512 + nq);
                fr[k * 2 + 1] = *(const float4*)(xs + (size_t)((t + 1) * 64 + sl + 1) * 512 + nq);
            }
        }
#pragma unroll
        for (int ks = 0; ks < 2; ++ks) {
            const int cc = ks * 4 + g;
            bf16x8 av[4], bv[4];
#pragma unroll
            for (int j = 0; j < 4; ++j) {
                const int n = wn + j * 16 + lr;
                const char* p = smX + n * 136 + ((cc ^ (n & 7)) << 4);
                union { unsigned long long u[2]; bf16x8 v; } tmp;
                tmp.u[0] = *(const unsigned long long*)(p);
                tmp.u[1] = *(const unsigned long long*)(p + 8);
                bv[j] = tmp.v;
            }
#pragma unroll
            for (int i = 0; i < 4; ++i) { const int rw = wm + i * 16 + lr;
                av[i] = *(const bf16x8*)(smA0 + rw * 128 + ((cc ^ (rw & 7)) * 16)); }
#pragma unroll
            for (int i = 0; i < 4; ++i)
#pragma unroll
                for (int j = 0; j < 4; ++j)
                    acc0[i][j] = __builtin_amdgcn_mfma_f32_16x16x32_bf16(av[i], bv[j], acc0[i][j], 0, 0, 0);
#pragma unroll
            for (int i = 0; i < 4; ++i) { const int rw = wm + i * 16 + lr;
                av[i] = *(const bf16x8*)(smA1 + rw * 128 + ((cc ^ (rw & 7)) * 16)); }
#pragma unroll
            for (int i = 0; i < 4; ++i)
#pragma unroll
                for (int j = 0; j < 4; ++j)
                    acc1[i][j] = __builtin_amdgcn_mfma_f32_16x16x32_bf16(av[i], bv[j], acc1[i][j], 0, 0, 0);
        }
        __syncthreads();
    }
    // sweep-B x preload issued BEFORE the epilogues (latency hidden under them)
#pragma unroll
    for (int k = 0; k < 4; ++k) {
        const int sl = k * 16 + sp2;
        fr[k * 2 + 0] = *(const float4*)(xs + (size_t)(sl) * 512 + nq);
        fr[k * 2 + 1] = *(const float4*)(xs + (size_t)(sl + 1) * 512 + nq);
    }
    epi_write_rm(acc0, smem);
    __syncthreads();
    epi_flush(smem, bufb + (size_t)bc * 131072 + n0 * 128, 512);
    epi_write_rm(acc1, smem);
    __syncthreads();
    epi_flush(smem, bufb + (size_t)bc * 131072 + 65536 + n0 * 128, 512);

    // ---- sweep B: v2w (x re-staged, L3-hot) --------------------------------
    f32x4 acc2[4][4] = {};
#pragma unroll 1
    for (int t = 0; t < 8; ++t) {
#pragma unroll
        for (int j = 0; j < 4; ++j) {
            const int row = w * 32 + j * 8 + rl;
            gload16(Wb2 + (size_t)row * 1024 + t * 128 + ((ch ^ (row & 7)) * 16),
                    smA0 + (w * 32 + j * 8) * 128);
        }
#pragma unroll
        for (int k = 0; k < 4; ++k) {
            const int sl = k * 16 + sp2;
            const float4 f0 = fr[k * 2 + 0];
            const float4 f1 = fr[k * 2 + 1];
            const unsigned p0 = f2bf(f0.x) | ((unsigned)f2bf(f1.x) << 16);
            const unsigned p1 = f2bf(f0.y) | ((unsigned)f2bf(f1.y) << 16);
            const unsigned p2 = f2bf(f0.z) | ((unsigned)f2bf(f1.z) << 16);
            const unsigned p3 = f2bf(f0.w) | ((unsigned)f2bf(f1.w) << 16);
            const int cl = sl >> 3, bic = (sl * 2) & 15;
#pragma unroll
            for (int i = 0; i < 4; ++i) {
                const int n = nq + i;
                const unsigned v = (i == 0) ? p0 : (i == 1) ? p1 : (i == 2) ? p2 : p3;
                *(unsigned*)(smX + n * 136 + ((cl ^ (n & 7)) << 4) + bic) = v;
            }
        }
        __syncthreads();
        if (t < 7) {
#pragma unroll
            for (int k = 0; k < 4; ++k) {
                const int sl = k * 16 + sp2;
                fr[k * 2 + 0] = *(const float4*)(xs + (size_t)((t + 1) * 64 + sl) * 512 + nq);
                fr[k * 2 + 1] = *(const float4*)(xs + (size_t)((t + 1) * 64 + sl + 1) * 512 + nq);
            }
        }
#pragma unroll
        for (int ks = 0; ks < 2; ++ks) {
            const int cc = ks * 4 + g;
            bf16x8 av[4], bv[4];
#pragma unroll
            for (int i = 0; i < 4; ++i) { const int rw = wm + i * 16 + lr;
                av[i] = *(const bf16x8*)(smA0 + rw * 128 + ((cc ^ (rw & 7)) * 16)); }
#pragma unroll
            for (int j = 0; j < 4; ++j) {
                const int n = wn + j * 16 + lr;
                const char* p = smX + n * 136 + ((cc ^ (n & 7)) << 4);
                union { unsigned long long u[2]; bf16x8 v; } tmp;
                tmp.u[0] = *(const unsigned long long*)(p);
                tmp.u[1] = *(const unsigned long long*)(p + 8);
                bv[j] = tmp.v;
            }
#pragma unroll
            for (int i = 0; i < 4; ++i)
#pragma unroll
                for (int j = 0; j < 4; ++j)
                    acc2[i][j] = __builtin_amdgcn_mfma_f32_16x16x32_bf16(av[i], bv[j], acc2[i][j], 0, 0, 0);
        }
        __syncthreads();
    }
    epi_write_tr(acc2, smem);
    __syncthreads();
    epi_flush(smem, v2t + (size_t)bc * 65536 + (size_t)n0 * 16384, 128);
}

// ---- k_kr: kx@krt -> kmat ; v1x@v1rt -> v1m -------------------------------
__global__ __launch_bounds__(256, 2) void k_kr(const unsigned short* __restrict__ bufb,
                                               const unsigned short* __restrict__ krt,
                                               const unsigned short* __restrict__ v1rt,
                                               unsigned short* __restrict__ kmat,
                                               unsigned short* __restrict__ v1m)
{
    __shared__ char smem[34816];
    char* smA = smem; char* smB = smem + 16384;
    const int mt = blockIdx.x, bc = blockIdx.y, c = bc & 15;
    const int w = threadIdx.x >> 6;
    f32x4 acc[4][4] = {};
    mmcore<8, 4, 4>((const char*)(bufb + (size_t)bc * 131072 + (size_t)mt * 65536), 1024,
                    (const char*)((mt ? v1rt : krt) + (size_t)c * 65536), 1024, acc, smA, smB,
                    (w >> 1) * 64, (w & 1) * 64);
    epi_write_rm(acc, smem);
    __syncthreads();
    epi_flush(smem, (mt ? v1m : kmat) + (size_t)bc * 16384, 128);
}

// ---- k_qat: fused q = x(fp32)@wqt, attn = softmax(q @ kmat^T); 48KB LDS ---
__global__ __launch_bounds__(256, 2) void k_qat(const float* __restrict__ x,
                                                const unsigned short* __restrict__ wqt,
                                                const unsigned short* __restrict__ kmat,
                                                unsigned short* __restrict__ attn)
{
    __shared__ char smem[49152];
    char* smA  = smem;
    char* smB  = smem + 16384;
    char* qlds = smem;               // q tile over dead GEMM1 staging
    char* smB2 = smem + 32768;       // GEMM2 B staging
    const int mt = blockIdx.x, bc = blockIdx.y, c = bc & 15;
    const int tid = threadIdx.x, w = tid >> 6, l = tid & 63, g = l >> 4, lr = l & 15;
    const int rl = l >> 3, ch = l & 7;
    const int wm = (w >> 1) * 64, wn = (w & 1) * 64;

    f32x4 acc[4][4] = {};
    {
        const float* Ax = x + (size_t)bc * 262144 + (size_t)(mt * 128) * 512;
        const char* Bw = (const char*)(wqt + (size_t)c * 65536);
        const int ar = tid >> 4, fq = tid & 15;
#pragma unroll 1
        for (int t = 0; t < 8; ++t) {
#pragma unroll
            for (int j = 0; j < 4; ++j) {
                const int row = w * 32 + j * 8 + rl;
                gload16(Bw + (size_t)row * 1024 + t * 128 + ((ch ^ (row & 7)) * 16),
                        smB + (w * 32 + j * 8) * 128);
            }
            float4 frq[8];
#pragma unroll
            for (int it = 0; it < 8; ++it) {
                const int row = it * 16 + ar;
                frq[it] = *(const float4*)(Ax + (size_t)row * 512 + t * 64 + fq * 4);
            }
#pragma unroll
            for (int it = 0; it < 8; ++it) {
                const int row = it * 16 + ar;
                ushort4 o = make_ushort4(f2bf(frq[it].x), f2bf(frq[it].y),
                                         f2bf(frq[it].z), f2bf(frq[it].w));
                *(ushort4*)(smA + row * 128 + (((fq >> 1) ^ (row & 7)) * 16) + (fq & 1) * 8) = o;
            }
            __syncthreads();
#pragma unroll
            for (int ks = 0; ks < 2; ++ks) {
                const int cc2 = ks * 4 + g;
                bf16x8 av[4], bv[4];
#pragma unroll
                for (int i = 0; i < 4; ++i) { const int rw = wm + i * 16 + lr;
                    av[i] = *(const bf16x8*)(smA + rw * 128 + ((cc2 ^ (rw & 7)) * 16)); }
#pragma unroll
                for (int j = 0; j < 4; ++j) { const int rw = wn + j * 16 + lr;
                    bv[j] = *(const bf16x8*)(smB + rw * 128 + ((cc2 ^ (rw & 7)) * 16)); }
#pragma unroll
                for (int i = 0; i < 4; ++i)
#pragma unroll
                    for (int j = 0; j < 4; ++j)
                        acc[i][j] = __builtin_amdgcn_mfma_f32_16x16x32_bf16(av[i], bv[j], acc[i][j], 0, 0, 0);
            }
            __syncthreads();
        }
    }
    {
        const int t = wn >> 6;
#pragma unroll
        for (int i = 0; i < 4; ++i)
#pragma unroll
            for (int j = 0; j < 4; ++j) {
                const int k6 = j * 16 + lr;
                const int chunk = k6 >> 3, eb = (k6 & 7) << 1;
#pragma unroll
                for (int r = 0; r < 4; ++r) {
                    const int row = wm + i * 16 + g * 4 + r;
                    *(unsigned short*)(qlds + t * 16384 + row * 128 +
                                       ((chunk ^ (row & 7)) << 4) + eb) = f2bf(acc[i][j][r]);
                }
            }
    }
    __syncthreads();

    f32x4 acc2[2][8] = {};
    const char* Kb = (const char*)(kmat + (size_t)bc * 16384);
#pragma unroll
    for (int t = 0; t < 2; ++t) {
#pragma unroll
        for (int j = 0; j < 4; ++j) {
            const int row = w * 32 + j * 8 + rl;
            gload16(Kb + (size_t)row * 256 + t * 128 + ((ch ^ (row & 7)) * 16),
                    smB2 + (w * 32 + j * 8) * 128);
        }
        __syncthreads();
#pragma unroll
        for (int ks = 0; ks < 2; ++ks) {
            const int cc2 = ks * 4 + g;
            bf16x8 av[2], bv[8];
#pragma unroll
            for (int i = 0; i < 2; ++i) { const int rw = w * 32 + i * 16 + lr;
                av[i] = *(const bf16x8*)(qlds + t * 16384 + rw * 128 + ((cc2 ^ (rw & 7)) * 16)); }
#pragma unroll
            for (int j = 0; j < 8; ++j) { const int rw = j * 16 + lr;
                bv[j] = *(const bf16x8*)(smB2 + rw * 128 + ((cc2 ^ (rw & 7)) * 16)); }
#pragma unroll
            for (int i = 0; i < 2; ++i)
#pragma unroll
                for (int j = 0; j < 8; ++j)
                    acc2[i][j] = __builtin_amdgcn_mfma_f32_16x16x32_bf16(av[i], bv[j], acc2[i][j], 0, 0, 0);
        }
        __syncthreads();
    }

    char* wsl = smem + w * 8704;
    unsigned short* ob = attn + (size_t)bc * 65536 + (size_t)(mt * 128 + w * 32) * 128;
#pragma unroll
    for (int i = 0; i < 2; ++i)
#pragma unroll
        for (int r = 0; r < 4; ++r) {
            float mx = -3e38f;
#pragma unroll
            for (int fj = 0; fj < 8; ++fj) mx = fmaxf(mx, acc2[i][fj][r]);
#pragma unroll
            for (int d = 1; d < 16; d <<= 1) mx = fmaxf(mx, __shfl_xor(mx, d));
            float s = 0.f, e[8];
#pragma unroll
            for (int fj = 0; fj < 8; ++fj) { e[fj] = __expf(acc2[i][fj][r] - mx); s += e[fj]; }
#pragma unroll
            for (int d = 1; d < 16; d <<= 1) s += __shfl_xor(s, d);
            const float inv = 1.f / s;
            const int rowh = i * 16 + g * 4 + r;
#pragma unroll
            for (int fj = 0; fj < 8; ++fj)
                *(unsigned short*)(wsl + rowh * 272 + (fj * 16 + lr) * 2) = f2bf(e[fj] * inv);
        }
#pragma unroll
    for (int rep = 0; rep < 8; ++rep) {
        const int row = rep * 4 + (l >> 4);
        *(short8*)((short*)ob + (size_t)row * 128 + (l & 15) * 8) =
            *(const short8*)(wsl + row * 272 + (l & 15) * 16);
    }
}

// ---- k_v: vt = v2t @ v1m^T-form  (= (v1@v2)^T) ----------------------------
__global__ __launch_bounds__(256, 2) void k_v(const unsigned short* __restrict__ v2t,
                                              const unsigned short* __restrict__ v1m,
                                              unsigned short* __restrict__ vt)
{
    __shared__ char smem[34816];
    char* smA = smem; char* smB = smem + 16384;
    const int mt = blockIdx.x, bc = blockIdx.y;
    const int w = threadIdx.x >> 6;
    f32x4 acc[4][4] = {};
    mmcore<2, 4, 4>((const char*)(v2t + (size_t)bc * 65536 + (size_t)mt * 16384), 256,
                    (const char*)(v1m + (size_t)bc * 16384), 256, acc, smA, smB,
                    (w >> 1) * 64, (w & 1) * 64);
    epi_write_rm(acc, smem);
    __syncthreads();
    epi_flush(smem, vt + (size_t)bc * 65536 + (size_t)mt * 16384, 128);
}

// ---- k_y: y = x + attn@v (fp32), stats, store y as bf16 -------------------
__global__ __launch_bounds__(256, 2) void k_y(const unsigned short* __restrict__ attn,
                                              const unsigned short* __restrict__ vt,
                                              const float* __restrict__ x,
                                              unsigned short* __restrict__ yb,
                                              float* __restrict__ stats)
{
    __shared__ char smem[34816];
    __shared__ float r1[4], r2[4];
    char* smA = smem; char* smB = smem + 16384;
    const int nx = blockIdx.x, my = blockIdx.y, bc = blockIdx.z, c = bc & 15;
    const int tid = threadIdx.x, w = tid >> 6, l = tid & 63, g = l >> 4, lr = l & 15;
    f32x4 acc[4][4] = {};
    mmcore<2, 4, 4>((const char*)(attn + (size_t)bc * 65536 + (size_t)my * 16384), 256,
                    (const char*)(vt + (size_t)bc * 65536 + (size_t)nx * 16384), 256, acc, smA, smB,
                    (w >> 1) * 64, (w & 1) * 64);
    const float* xw = x + (size_t)bc * 262144 + (size_t)my * 128 * 512 + nx * 128;
    const int wm = (w >> 1) * 64, wn = (w & 1) * 64;
    float lsum = 0.f, lss = 0.f;
#pragma unroll
    for (int i = 0; i < 4; ++i)
#pragma unroll
        for (int j = 0; j < 4; ++j)
#pragma unroll
            for (int r = 0; r < 4; ++r) {
                const int row = wm + i * 16 + g * 4 + r, col = wn + j * 16 + lr;
                const float yv = acc[i][j][r] + xw[(size_t)row * 512 + col];
                lsum += yv; lss += yv * yv;
                *(unsigned short*)(smem + row * 272 + col * 2) = f2bf(yv);
            }
#pragma unroll
    for (int d = 32; d >= 1; d >>= 1) { lsum += __shfl_xor(lsum, d); lss += __shfl_xor(lss, d); }
    if (l == 0) { r1[w] = lsum; r2[w] = lss; }
    __syncthreads();
    epi_flush(smem, yb + (size_t)bc * 262144 + (size_t)my * 128 * 512 + nx * 128, 512);
    if (tid == 0) {
        atomicAdd(&stats[c * 2 + 0], r1[0] + r1[1] + r1[2] + r1[3]);
        atomicAdd(&stats[c * 2 + 1], r2[0] + r2[1] + r2[2] + r2[3]);
    }
}

// out(fp32) = yb(bf16)*scale[c] + shift[c], finalize inlined via LDS
__global__ __launch_bounds__(256) void k_norm(const unsigned short* __restrict__ yb,
                                              float* __restrict__ out,
                                              const float* __restrict__ stats,
                                              const float* __restrict__ gamma,
                                              const float* __restrict__ beta)
{
    __shared__ float ssc[16], ssh[16];
    if (threadIdx.x < 16) {
        const int c = threadIdx.x;
        const float cnt  = 2097152.f;
        const float mean = stats[c * 2 + 0] / cnt;
        const float var  = stats[c * 2 + 1] / cnt - mean * mean;
        const float sc   = rsqrtf(var + 1e-5f) * gamma[c];
        ssc[c] = sc;
        ssh[c] = beta[c] - mean * sc;
    }
    __syncthreads();
    const int tot = 4194304;
    for (int i = blockIdx.x * 256 + threadIdx.x; i < tot; i += gridDim.x * 256) {
        const long e = (long)i * 8;
        const int c = (int)(e >> 18) & 15;
        const float sc = ssc[c];
        const float sh = ssh[c];
        short8 v = ((const short8*)yb)[i];
        float4 o0, o1;
        o0.x = bf2f((unsigned short)v[0]) * sc + sh;
        o0.y = bf2f((unsigned short)v[1]) * sc + sh;
        o0.z = bf2f((unsigned short)v[2]) * sc + sh;
        o0.w = bf2f((unsigned short)v[3]) * sc + sh;
        o1.x = bf2f((unsigned short)v[4]) * sc + sh;
        o1.y = bf2f((unsigned short)v[5]) * sc + sh;
        o1.z = bf2f((unsigned short)v[6]) * sc + sh;
        o1.w = bf2f((unsigned short)v[7]) * sc + sh;
        ((float4*)out)[(size_t)i * 2 + 0] = o0;
        ((float4*)out)[(size_t)i * 2 + 1] = o1;
    }
}

extern "C" void kernel_launch(void* const* d_in, const int* in_sizes, int n_in,
                              void* d_out, int out_size, void* d_ws, size_t ws_size,
                              hipStream_t stream)
{
    (void)in_sizes; (void)n_in; (void)out_size; (void)ws_size;
    const float* x     = (const float*)d_in[0];
    const float* wq    = (const float*)d_in[1];
    const float* kl    = (const float*)d_in[2];
    const float* kr    = (const float*)d_in[3];
    const float* v1l   = (const float*)d_in[4];
    const float* v1r   = (const float*)d_in[5];
    const float* v2w   = (const float*)d_in[6];
    const float* gamma = (const float*)d_in[7];
    const float* beta  = (const float*)d_in[8];
    float* out = (float*)d_out;
    char*  ws  = (char*)d_ws;

    unsigned short* yb   = (unsigned short*)(ws + OB_XB);
    unsigned short* klb  = (unsigned short*)(ws + OB_KLB);
    unsigned short* v1lb = (unsigned short*)(ws + OB_V1LB);
    unsigned short* v2wb = (unsigned short*)(ws + OB_V2WB);
    unsigned short* wqt  = (unsigned short*)(ws + OB_WQT);
    unsigned short* krt  = (unsigned short*)(ws + OB_KRT);
    unsigned short* v1rt = (unsigned short*)(ws + OB_V1RT);
    unsigned short* bufb = (unsigned short*)(ws + OB_BUF);
    unsigned short* v2t  = (unsigned short*)(ws + OB_V2T);
    unsigned short* kmat = (unsigned short*)(ws + OB_KM);
    unsigned short* v1m  = (unsigned short*)(ws + OB_V1M);
    unsigned short* attn = (unsigned short*)(ws + OB_ATT);
    unsigned short* vt   = (unsigned short*)(ws + OB_VT);
    float*          st   = (float*)(ws + OB_ST);

    hipLaunchKernelGGL(k_prep,  dim3(960),       dim3(256), 0, stream,
                       kl, v1l, v2w, wq, kr, v1r, klb, v1lb, v2wb, wqt, krt, v1rt, st);
    hipLaunchKernelGGL(k_wx,    dim3(4, 128),    dim3(256), 0, stream, klb, v1lb, v2wb, x, bufb, v2t);
    hipLaunchKernelGGL(k_kr,    dim3(2, 128),    dim3(256), 0, stream, bufb, krt, v1rt, kmat, v1m);
    hipLaunchKernelGGL(k_qat,   dim3(4, 128),    dim3(256), 0, stream, x, wqt, kmat, attn);
    hipLaunchKernelGGL(k_v,     dim3(4, 128),    dim3(256), 0, stream, v2t, v1m, vt);
    hipLaunchKernelGGL(k_y,     dim3(4, 4, 128), dim3(256), 0, stream, attn, vt, x, yb, st);
    hipLaunchKernelGGL(k_norm,  dim3(2048),      dim3(256), 0, stream, yb, out, st, gamma, beta);
}